// Round 4
// baseline (94.302 us; speedup 1.0000x reference)
//
#include <hip/hip_runtime.h>

#define HH 512
#define WW 512
#define HW (HH * WW)
#define RR 5
#define KS 11
#define EPS_F 1e-5f
#define NLOG2E 1.44269504088896340736f
#define TW 64                 // output tile width
#define TH 4                  // output rows per tile
#define TPB 4                 // tiles per block (sliding window)
#define CH (TH * TPB)         // 16 output rows per block
#define BY 5                  // 320 threads = 5 waves
#define SW (TW + 2 * RR)      // 74: strip width (x-halo)
#define SH (TH + 2 * RR)      // 14: live window height
#define NSTRIP (SW * TH)      // 296 strip pixels (one per pass-V thread)
#define RS 16                 // ring slots (pow2 >= SH+2)
#define PRO (SW * SH)         // 1036 prologue pixels

typedef float f2 __attribute__((ext_vector_type(2)));
__device__ __forceinline__ f2 fma2(f2 a, f2 b, f2 c) { return __builtin_elementwise_fma(a, b, c); }

// R13 = R12 with the staging-row off-by-4 fixed (was gy = y0+13+ly, slots
// expect y0+9+ly = y0+TH+RR+ly; absmax 0.43 -> correct).
// R12 theory (unchanged): R10 (VALU -35%, LDS 53KB) = +12us and R11 (VMEM
// restructure) = -2us ==> kernel is occupancy x barrier-coupling bound, all
// pipes <=30%. Attack the structure:
//  - block owns 16 output rows (4 TH=4 tiles); halo rows live in a 16-slot
//    LDS row ring. Prologue stages 14 rows once; each tile stages only 4 new
//    rows. Staged pixels/output: 4.05 -> 1.9.
//  - staging loads (1 px/thread: psf+3ch) are ISSUED before the tap loop and
//    ds-written after the post-V barrier -> pass V hides their latency (T14).
//  - 2 barriers/tile (post-H barrier is redundant: sync1(k+1) already orders
//    cp rewrites against pass-H(k) reads). 12 -> 9 barriers per 16 rows.
//  - ring schedule verified: k=0 writes slots 14,15,0,1 (rows 14..17);
//    k=1 -> 2..5 (18..21); k=2 -> 6..9 (22..25); never clobbers a live row.
// LDS = ring 18.9KB + cp 28.4KB = 47.3KB -> 3 blocks/CU; launch_bounds(320,4)
// pins VGPR<=128 so residency stays VGPR-safe.
__global__ __launch_bounds__(320, 4) void gauss_psf_kernel(const float* __restrict__ image,
                                                           const float* __restrict__ psf,
                                                           float* __restrict__ out) {
    __shared__ float4 ring[RS * SW];    // 16 row slots x 74 = 18.9 KB (t,i0,i1,i2)
    __shared__ float4 cp[6 * NSTRIP];   // class planes (ch0,ch1,ch2,w), 28.4 KB

    const int tx  = threadIdx.x;            // 0..63
    const int ty  = threadIdx.y;            // 0..4
    const int tid = ty * 64 + tx;           // 0..319
    const int bx0 = blockIdx.x * TW;
    const int byc = blockIdx.y * CH;        // chunk base row
    const int b   = blockIdx.z;

    const float* pw   = psf + (size_t)b * HW;
    const float* img0 = image + (size_t)b * 3 * HW;

    // ---- Prologue: stage rows byc-5 .. byc+8 into slots 0..13 ----
#pragma unroll
    for (int base = 0; base < PRO; base += 320) {
        const int idx = base + tid;
        if (idx < PRO) {
            const int row = idx / SW, col = idx - row * SW;
            const int gy = byc - RR + row, gx = bx0 - RR + col;
            const bool in = ((unsigned)gy < (unsigned)HH) && ((unsigned)gx < (unsigned)WW);
            const int cy = gy < 0 ? 0 : (gy > HH - 1 ? HH - 1 : gy);
            const int cx = gx < 0 ? 0 : (gx > WW - 1 ? WW - 1 : gx);
            const int ni = cy * WW + cx;
            const float w  = pw[ni];
            const float i0 = img0[ni];
            const float i1 = img0[ni + HW];
            const float i2 = img0[ni + 2 * HW];
            const float a = -NLOG2E * __builtin_amdgcn_rcpf(fmaf(2.0f * w, w, EPS_F));
            const float t = in ? __builtin_amdgcn_exp2f(a) : 0.0f;
            ring[row * SW + col] = make_float4(t, i0, i1, i2);  // slot==row in prologue
        }
    }
    __syncthreads();

    const int ly = tid / SW;                // 0..3 (valid when tid < NSTRIP)
    const int lx = tid - ly * SW;           // 0..73
    const int gxs = bx0 - RR + lx;
    const int cxs = gxs < 0 ? 0 : (gxs > WW - 1 ? WW - 1 : gxs);
    const bool xin = (unsigned)gxs < (unsigned)WW;

#pragma unroll
    for (int k = 0; k < TPB; ++k) {
        const int y0 = byc + TH * k;

        // -- issue next-tile staging loads (rows y0+9..y0+12), write after sync1 --
        float sw_ = 0.0f, s0 = 0.0f, s1 = 0.0f, s2 = 0.0f;
        bool stin = false;
        if (k < TPB - 1 && tid < NSTRIP) {
            const int gy = y0 + TH + RR + ly;                  // y0 + 9 + ly  (ring row 4k+14+ly)
            const int cy = gy > HH - 1 ? HH - 1 : gy;          // gy >= 0 always here
            const int ni = cy * WW + cxs;
            sw_ = pw[ni];
            s0  = img0[ni];
            s1  = img0[ni + HW];
            s2  = img0[ni + 2 * HW];
            stin = (gy < HH) && xin;
        }

        // -- Pass V: one strip pixel per thread, taps from the ring --
        f2 a0p[3], a1p[3], a2p[3], awp[3];
#pragma unroll
        for (int p = 0; p < 3; ++p) {
            a0p[p] = (f2)0.0f; a1p[p] = (f2)0.0f; a2p[p] = (f2)0.0f; awp[p] = (f2)0.0f;
        }

        if (tid < NSTRIP) {
#pragma unroll
            for (int r = 0; r < KS; ++r) {
                const int slot = (TH * k + ly + r) & (RS - 1);
                const float4 v = ring[slot * SW + lx];         // ds_read_b128
                const float t = v.x, i0 = v.y, i1 = v.z, i2 = v.w;

                const float t2 = t * t, t4 = t2 * t2, t8 = t4 * t4;
                const float t9 = t8 * t, t16 = t8 * t8, t25 = t16 * t9;

                const int ii = (r - RR) * (r - RR);            // constexpr after unroll
                const float u = ii == 0 ? 1.0f : ii == 1 ? t : ii == 4 ? t4
                              : ii == 9 ? t9 : ii == 16 ? t16 : t25;   // t^(i^2)

                const f2 u2  = {u, u};
                const f2 f01 = u2 * (f2){1.0f, t};
                const f2 f23 = u2 * (f2){t4, t9};
                const f2 f45 = u2 * (f2){t16, t25};

                const f2 i0v = {i0, i0}, i1v = {i1, i1}, i2v = {i2, i2};
                a0p[0] = fma2(i0v, f01, a0p[0]);
                a0p[1] = fma2(i0v, f23, a0p[1]);
                a0p[2] = fma2(i0v, f45, a0p[2]);
                a1p[0] = fma2(i1v, f01, a1p[0]);
                a1p[1] = fma2(i1v, f23, a1p[1]);
                a1p[2] = fma2(i1v, f45, a1p[2]);
                a2p[0] = fma2(i2v, f01, a2p[0]);
                a2p[1] = fma2(i2v, f23, a2p[1]);
                a2p[2] = fma2(i2v, f45, a2p[2]);
                awp[0] += f01;
                awp[1] += f23;
                awp[2] += f45;
            }
        }
        __syncthreads();    // sync1: all ring reads (k) done; cp(k-1) reads done

        // -- staged ring write: slots (4k+14..4k+17)&15 = rows y0+9..y0+12 --
        if (k < TPB - 1 && tid < NSTRIP) {
            const float a = -NLOG2E * __builtin_amdgcn_rcpf(fmaf(2.0f * sw_, sw_, EPS_F));
            const float t = stin ? __builtin_amdgcn_exp2f(a) : 0.0f;
            ring[((TH * k + SH + ly) & (RS - 1)) * SW + lx] = make_float4(t, s0, s1, s2);
        }

        if (tid < NSTRIP) {
#pragma unroll
            for (int p = 0; p < 3; ++p) {                      // 6 ds_write_b128
                cp[(2 * p) * NSTRIP + tid]     = make_float4(a0p[p].x, a1p[p].x, a2p[p].x, awp[p].x);
                cp[(2 * p + 1) * NSTRIP + tid] = make_float4(a0p[p].y, a1p[p].y, a2p[p].y, awp[p].y);
            }
        }
        __syncthreads();    // sync2: cp(k) + ring writes visible

        // -- Pass H: 256 output pixels; no trailing barrier needed --
        if (tid < TW * TH) {
            const int hx = tid & 63, hy = tid >> 6;
            const int hb = hy * SW + hx;
            f2 s01 = (f2)0.0f, s2w = (f2)0.0f;
#pragma unroll
            for (int j = 0; j < KS; ++j) {
                const int jj = (j - RR) * (j - RR);            // constexpr
                const int ai = jj == 0 ? 0 : jj == 1 ? 1 : jj == 4 ? 2
                             : jj == 9 ? 3 : jj == 16 ? 4 : 5;
                const float4 v = cp[ai * NSTRIP + hb + j];     // ds_read_b128
                s01 += (f2){v.x, v.y};
                s2w += (f2){v.z, v.w};
            }

            const float swv = s2w.y;                           // >= 1 (center tap)
            float inv = __builtin_amdgcn_rcpf(swv);
            inv = inv * (2.0f - swv * inv);                    // Newton: ~1e-7 rel
            const int x = bx0 + hx, y = y0 + hy;
            const int oi = y * WW + x;
            float* outb = out + (size_t)b * 3 * HW;
            outb[oi]          = s01.x * inv;
            outb[HW + oi]     = s01.y * inv;
            outb[2 * HW + oi] = s2w.x * inv;
        }
    }
}

extern "C" void kernel_launch(void* const* d_in, const int* in_sizes, int n_in,
                              void* d_out, int out_size, void* d_ws, size_t ws_size,
                              hipStream_t stream) {
    const float* image = (const float*)d_in[0];
    const float* psf   = (const float*)d_in[1];
    float* out = (float*)d_out;

    dim3 block(TW, BY, 1);                 // 320 threads = 5 waves
    dim3 grid(WW / TW, HH / CH, 4);        // 8 x 32 x 4 = 1024 blocks
    gauss_psf_kernel<<<grid, block, 0, stream>>>(image, psf, out);
}

// Round 5
// 84.237 us; speedup vs baseline: 1.1195x; 1.1195x over previous
//
#include <hip/hip_runtime.h>

#define HH 512
#define WW 512
#define HW (HH * WW)
#define RR 5
#define KS 11
#define EPS_F 1e-5f
#define NLOG2E 1.44269504088896340736f
#define TW 64                 // output tile width
#define TH 4                  // output tile height
#define BY 5                  // 320 threads = 5 waves
#define SW 76                 // padded strip width (even -> 8B-aligned float2 staging)
#define SH (TH + 2 * RR)      // 14: strip height (y-halo)
#define NV (SW * TH)          // 304 pass-V threads (cols 0 and 75 are pad, never read by H)
#define NT (SH * SW)          // 1064 strip pixels
#define F2W (SW / 2)          // 38 float2 items per strip row
#define NF2 (NT / 2)          // 532 float2 stage items

typedef float f2 __attribute__((ext_vector_type(2)));
__device__ __forceinline__ f2 fma2(f2 a, f2 b, f2 c) { return __builtin_elementwise_fma(a, b, c); }

// R14 = R11 (best: 84.5us) + vectorized/fast-path staging. Evidence ledger:
// resident blocks/CU correlates monotonically with dur (5blk=84.5, 4=86.5,
// 3=94-98) while VALU -35% (R10), VMEM restructure (R11), halo amortization
// (R13) each moved <= +-2us ==> stall/convoy-bound; per-block serial chain is
// the cost. Attack the fully-exposed phase-1 chain without touching the
// 28.4KB/5-blocks footprint:
//  - strip padded to SW=76, base bx0-6 (even) -> 8B-aligned float2 staging:
//    4x global_load_dwordx2 per 2-px item; wave VMEM 65->34/block, phase-1
//    VALU ~700->~380 wave-insts, 2 staging rounds instead of 4.
//  - block-uniform fast path (73% of blocks fully interior): no clamps, no
//    OOB mask (s_cbranch, zero divergence). Boundary blocks keep R11 logic.
//  - tap loop, cp overlay, barriers, pass H: byte-identical to R11.
// LDS union = cp = 6*304*16 = 28.5KB -> still 5 blocks/CU (threshold 32KB).
// Falsifier: flat (+-1us) => phase-1 immaterial => next round = 1-barrier
// shuffle-H restructure (no cp, 32 waves/CU).
__global__ __launch_bounds__(320) void gauss_psf_kernel(const float* __restrict__ image,
                                                        const float* __restrict__ psf,
                                                        float* __restrict__ out) {
    __shared__ float4 sm[6 * NV];       // 1824 float4 = 28.5 KB (union: strip[0..1063] | cp)

    const int tx  = threadIdx.x;            // 0..63
    const int ty  = threadIdx.y;            // 0..4
    const int tid = ty * 64 + tx;           // 0..319
    const int bx0 = blockIdx.x * TW;
    const int by0 = blockIdx.y * TH;
    const int b   = blockIdx.z;

    const float* pw   = psf + (size_t)b * HW;
    const float* img0 = image + (size_t)b * 3 * HW;

    // ---- Phase 1: stage (t, ch0, ch1, ch2) for the 14 x 76 strip ----
    const bool interior = (bx0 >= TW) && (bx0 + TW + RR + 1 <= WW) &&
                          (by0 >= 2 * TH) && (by0 + TH + RR <= HH);
    if (interior) {
        // fast path: all addresses in-bounds, gx even -> aligned dwordx2
#pragma unroll
        for (int it = 0; it < 2; ++it) {
            const int idx = tid + it * 320;
            if (idx < NF2) {
                const int row = idx / F2W, c2 = idx - row * F2W;
                const int gy = by0 - RR + row;
                const int gx = bx0 - (RR + 1) + 2 * c2;
                const int ni = gy * WW + gx;
                const float2 wv = *(const float2*)(pw + ni);
                const float2 v0 = *(const float2*)(img0 + ni);
                const float2 v1 = *(const float2*)(img0 + ni + HW);
                const float2 v2 = *(const float2*)(img0 + ni + 2 * HW);
                const float ta = __builtin_amdgcn_exp2f(
                    -NLOG2E * __builtin_amdgcn_rcpf(fmaf(2.0f * wv.x, wv.x, EPS_F)));
                const float tb = __builtin_amdgcn_exp2f(
                    -NLOG2E * __builtin_amdgcn_rcpf(fmaf(2.0f * wv.y, wv.y, EPS_F)));
                const int si = row * SW + 2 * c2;
                sm[si]     = make_float4(ta, v0.x, v1.x, v2.x);
                sm[si + 1] = make_float4(tb, v0.y, v1.y, v2.y);
            }
        }
    } else {
        // boundary blocks: per-px clamped + masked (R11 semantics)
#pragma unroll
        for (int it = 0; it < 2; ++it) {
            const int idx = tid + it * 320;
            if (idx < NF2) {
                const int row = idx / F2W, c2 = idx - row * F2W;
                const int gy = by0 - RR + row;
                const int cy = gy < 0 ? 0 : (gy > HH - 1 ? HH - 1 : gy);
#pragma unroll
                for (int q = 0; q < 2; ++q) {
                    const int gx = bx0 - (RR + 1) + 2 * c2 + q;
                    const bool in = ((unsigned)gy < (unsigned)HH) && ((unsigned)gx < (unsigned)WW);
                    const int cx = gx < 0 ? 0 : (gx > WW - 1 ? WW - 1 : gx);
                    const int ni = cy * WW + cx;
                    const float w  = pw[ni];
                    const float i0 = img0[ni];
                    const float i1 = img0[ni + HW];
                    const float i2 = img0[ni + 2 * HW];
                    const float a = -NLOG2E * __builtin_amdgcn_rcpf(fmaf(2.0f * w, w, EPS_F));
                    const float t = in ? __builtin_amdgcn_exp2f(a) : 0.0f;
                    sm[row * SW + 2 * c2 + q] = make_float4(t, i0, i1, i2);
                }
            }
        }
    }
    __syncthreads();

    // ---- Pass V: 304 strip pixels, one per thread; LDS-only tap loop ----
    // Accumulators at function scope: live across the strip->cp overlay barrier.
    f2 a0p[3], a1p[3], a2p[3], awp[3];
#pragma unroll
    for (int p = 0; p < 3; ++p) {
        a0p[p] = (f2)0.0f; a1p[p] = (f2)0.0f; a2p[p] = (f2)0.0f; awp[p] = (f2)0.0f;
    }

    if (tid < NV) {
        // tid = ly*SW + lx exactly; taps at +r*SW are compile-time imm offsets
#pragma unroll
        for (int r = 0; r < KS; ++r) {
            const float4 v = sm[tid + r * SW];                 // 1 ds_read_b128, imm off
            const float t = v.x, i0 = v.y, i1 = v.z, i2 = v.w;

            const float t2 = t * t, t4 = t2 * t2, t8 = t4 * t4;
            const float t9 = t8 * t, t16 = t8 * t8, t25 = t16 * t9;

            const int ii = (r - RR) * (r - RR);                // constexpr after unroll
            const float u = ii == 0 ? 1.0f : ii == 1 ? t : ii == 4 ? t4
                          : ii == 9 ? t9 : ii == 16 ? t16 : t25;   // t^(i^2)

            const f2 u2  = {u, u};
            const f2 f01 = u2 * (f2){1.0f, t};                 // t^(i^2+{0,1})
            const f2 f23 = u2 * (f2){t4, t9};                  // t^(i^2+{4,9})
            const f2 f45 = u2 * (f2){t16, t25};                // t^(i^2+{16,25})

            const f2 i0v = {i0, i0}, i1v = {i1, i1}, i2v = {i2, i2};
            a0p[0] = fma2(i0v, f01, a0p[0]);
            a0p[1] = fma2(i0v, f23, a0p[1]);
            a0p[2] = fma2(i0v, f45, a0p[2]);
            a1p[0] = fma2(i1v, f01, a1p[0]);
            a1p[1] = fma2(i1v, f23, a1p[1]);
            a1p[2] = fma2(i1v, f45, a1p[2]);
            a2p[0] = fma2(i2v, f01, a2p[0]);
            a2p[1] = fma2(i2v, f23, a2p[1]);
            a2p[2] = fma2(i2v, f45, a2p[2]);
            awp[0] += f01;
            awp[1] += f23;
            awp[2] += f45;
        }
    }
    __syncthreads();                        // strip dead -> cp may reuse the union

    if (tid < NV) {
#pragma unroll
        for (int p = 0; p < 3; ++p) {                          // 6 ds_write_b128
            sm[(2 * p) * NV + tid]     = make_float4(a0p[p].x, a1p[p].x, a2p[p].x, awp[p].x);
            sm[(2 * p + 1) * NV + tid] = make_float4(a0p[p].y, a1p[p].y, a2p[p].y, awp[p].y);
        }
    }
    __syncthreads();

    // ---- Pass H: 256 output pixels (waves 0-3); wave 4 exits uniformly ----
    if (tid < TW * TH) {
        const int hx = tid & 63, hy = tid >> 6;
        const int hb = hy * SW + hx + 1;    // strip col of (y, x-RR+j) at j=0 (base bx0-6)
        f2 s01 = (f2)0.0f, s2w = (f2)0.0f;
#pragma unroll
        for (int j = 0; j < KS; ++j) {
            const int jj = (j - RR) * (j - RR);                // constexpr
            const int ai = jj == 0 ? 0 : jj == 1 ? 1 : jj == 4 ? 2
                         : jj == 9 ? 3 : jj == 16 ? 4 : 5;
            const float4 v = sm[ai * NV + hb + j];             // ds_read_b128, imm off
            s01 += (f2){v.x, v.y};                             // pk_add
            s2w += (f2){v.z, v.w};
        }

        const float sw = s2w.y;                                // >= 1 (center tap)
        float inv = __builtin_amdgcn_rcpf(sw);
        inv = inv * (2.0f - sw * inv);                         // Newton: ~1e-7 rel
        const int x = bx0 + hx, y = by0 + hy;
        const int oi = y * WW + x;
        float* outb = out + (size_t)b * 3 * HW;
        outb[oi]          = s01.x * inv;
        outb[HW + oi]     = s01.y * inv;
        outb[2 * HW + oi] = s2w.x * inv;
    }
}

extern "C" void kernel_launch(void* const* d_in, const int* in_sizes, int n_in,
                              void* d_out, int out_size, void* d_ws, size_t ws_size,
                              hipStream_t stream) {
    const float* image = (const float*)d_in[0];
    const float* psf   = (const float*)d_in[1];
    float* out = (float*)d_out;

    dim3 block(TW, BY, 1);                 // 320 threads = 5 waves
    dim3 grid(WW / TW, HH / TH, 4);        // 8 x 128 x 4 = 4096 blocks
    gauss_psf_kernel<<<grid, block, 0, stream>>>(image, psf, out);
}

// Round 6
// 83.328 us; speedup vs baseline: 1.1317x; 1.0109x over previous
//
#include <hip/hip_runtime.h>

#define HH 512
#define WW 512
#define HW (HH * WW)
#define RR 5
#define KS 11
#define EPS_F 1e-5f
#define NLOG2E 1.44269504088896340736f
#define OPW 54                // outputs per wave (64 lanes - 10 halo)
#define NG 10                 // column groups: 9*54 + overlap group at 458

typedef float f2 __attribute__((ext_vector_type(2)));
__device__ __forceinline__ f2 fma2(f2 a, f2 b, f2 c) { return __builtin_elementwise_fma(a, b, c); }

// R15: zero-barrier wave-autonomous restructure. Ledger: only resident-block
// count ever moved dur (5blk=84.5, 4=86.5, 3=94-98); VALU-35% / VMEM / halo /
// staging-vectorization experiments all +-2us; all pipes <=30% busy at ~40us
// kernel ==> convoy-bound (5 barrier-coupled waves serialize per-phase
// latency, x16 sequential blocks/CU). This kernel has NO __syncthreads:
//  - wave = one output row x 54 cols (lanes carry +-5 x-halo). V inputs
//    loaded straight from global (block = 4 consecutive rows, same col group
//    -> L1 absorbs 4x row reuse; L2 the remaining ~2.75x).
//  - pass H via PRIVATE per-wave LDS scratch (6KB): same-wave ds_write ->
//    ds_read needs only lgkmcnt (compiler-inserted), no barrier.
//  - t recomputed per row-use (11x): VALU has 4x headroom, trade is free.
//  - cols 458..485 computed twice (g=8,g=9) bitwise-identically: benign.
// LDS 24.6KB/block; launch_bounds(256,6) caps VGPR at 84 -> 24 waves/CU,
// all independent. Falsifier: flat => stall is intra-wave dep latency, not
// convoy; attack exp2/rcp chain + ILP next.
__global__ __launch_bounds__(256, 6) void gauss_psf_kernel(const float* __restrict__ image,
                                                           const float* __restrict__ psf,
                                                           float* __restrict__ out) {
    __shared__ float4 smH[4][6][64];    // per-wave private class planes, 24.6 KB

    const int lane = threadIdx.x;           // 0..63
    const int ty   = threadIdx.y;           // 0..3 (wave id in block)
    const int g    = blockIdx.x;            // 0..9 column group
    const int y    = blockIdx.y * 4 + ty;   // output row
    const int b    = blockIdx.z;

    const int c0   = (g == NG - 1) ? (WW - OPW) : g * OPW;
    const int col  = c0 - RR + lane;        // this lane's column
    const int colc = col < 0 ? 0 : (col > WW - 1 ? WW - 1 : col);
    const float xm = ((unsigned)col < (unsigned)WW) ? 1.0f : 0.0f;

    const float* pw   = psf + (size_t)b * HW;
    const float* img0 = image + (size_t)b * 3 * HW;

    // ---- Pass V: 11 taps straight from global, accumulate 6 class pairs ----
    f2 a0p[3], a1p[3], a2p[3], awp[3];
#pragma unroll
    for (int p = 0; p < 3; ++p) {
        a0p[p] = (f2)0.0f; a1p[p] = (f2)0.0f; a2p[p] = (f2)0.0f; awp[p] = (f2)0.0f;
    }

    auto tap = [&](int r, float t, float i0, float i1, float i2) {
        const float t2 = t * t, t4 = t2 * t2, t8 = t4 * t4;
        const float t9 = t8 * t, t16 = t8 * t8, t25 = t16 * t9;

        const int ii = (r - RR) * (r - RR);                // constexpr after unroll
        const float u = ii == 0 ? 1.0f : ii == 1 ? t : ii == 4 ? t4
                      : ii == 9 ? t9 : ii == 16 ? t16 : t25;   // t^(i^2)

        const f2 u2  = {u, u};
        const f2 f01 = u2 * (f2){1.0f, t};                 // t^(i^2+{0,1})
        const f2 f23 = u2 * (f2){t4, t9};                  // t^(i^2+{4,9})
        const f2 f45 = u2 * (f2){t16, t25};                // t^(i^2+{16,25})

        const f2 i0v = {i0, i0}, i1v = {i1, i1}, i2v = {i2, i2};
        a0p[0] = fma2(i0v, f01, a0p[0]);
        a0p[1] = fma2(i0v, f23, a0p[1]);
        a0p[2] = fma2(i0v, f45, a0p[2]);
        a1p[0] = fma2(i1v, f01, a1p[0]);
        a1p[1] = fma2(i1v, f23, a1p[1]);
        a1p[2] = fma2(i1v, f45, a1p[2]);
        a2p[0] = fma2(i2v, f01, a2p[0]);
        a2p[1] = fma2(i2v, f23, a2p[1]);
        a2p[2] = fma2(i2v, f45, a2p[2]);
        awp[0] += f01;
        awp[1] += f23;
        awp[2] += f45;
    };

    if (blockIdx.y >= 2 && blockIdx.y <= 125) {
        // y-interior (124/128): no row clamp, no row mask; imm-offset row walk
        const float* pb = img0 + (size_t)(y - RR) * WW + colc;
        const float* wb = pw + (size_t)(y - RR) * WW + colc;
#pragma unroll
        for (int r = 0; r < KS; ++r) {
            const float w  = wb[r * WW];
            const float i0 = pb[r * WW];
            const float i1 = pb[r * WW + HW];
            const float i2 = pb[r * WW + 2 * HW];
            const float a = -NLOG2E * __builtin_amdgcn_rcpf(fmaf(2.0f * w, w, EPS_F));
            const float t = xm * __builtin_amdgcn_exp2f(a);
            tap(r, t, i0, i1, i2);
        }
    } else {
#pragma unroll
        for (int r = 0; r < KS; ++r) {
            const int gy = y - RR + r;
            const int ry = gy < 0 ? 0 : (gy > HH - 1 ? HH - 1 : gy);
            const float ym = ((unsigned)gy < (unsigned)HH) ? 1.0f : 0.0f;
            const int ni = ry * WW + colc;
            const float w  = pw[ni];
            const float i0 = img0[ni];
            const float i1 = img0[ni + HW];
            const float i2 = img0[ni + 2 * HW];
            const float a = -NLOG2E * __builtin_amdgcn_rcpf(fmaf(2.0f * w, w, EPS_F));
            const float t = xm * ym * __builtin_amdgcn_exp2f(a);
            tap(r, t, i0, i1, i2);
        }
    }

    // ---- Per-wave scratch write (no barrier: same-wave lgkmcnt ordering) ----
#pragma unroll
    for (int p = 0; p < 3; ++p) {                          // 6 ds_write_b128
        smH[ty][2 * p][lane]     = make_float4(a0p[p].x, a1p[p].x, a2p[p].x, awp[p].x);
        smH[ty][2 * p + 1][lane] = make_float4(a0p[p].y, a1p[p].y, a2p[p].y, awp[p].y);
    }

    // ---- Pass H: read own wave's class planes at lanes lb..lb+10 ----
    const int lm = lane - RR;
    const int lb = lm < 0 ? 0 : (lm > OPW - 1 ? OPW - 1 : lm);   // clamp keeps reads in-plane
    f2 s01 = (f2)0.0f, s2w = (f2)0.0f;
#pragma unroll
    for (int j = 0; j < KS; ++j) {
        const int jj = (j - RR) * (j - RR);                // constexpr
        const int ai = jj == 0 ? 0 : jj == 1 ? 1 : jj == 4 ? 2
                     : jj == 9 ? 3 : jj == 16 ? 4 : 5;
        const float4 v = smH[ty][ai][lb + j];              // ds_read_b128, imm off
        s01 += (f2){v.x, v.y};                             // pk_add
        s2w += (f2){v.z, v.w};
    }

    if ((unsigned)lm < OPW) {                              // lanes 5..58 store
        const float swv = s2w.y;                           // >= 1 (center tap)
        float inv = __builtin_amdgcn_rcpf(swv);
        inv = inv * (2.0f - swv * inv);                    // Newton: ~1e-7 rel
        const int oi = y * WW + col;                       // col = c0 + lm, in [0,511]
        float* outb = out + (size_t)b * 3 * HW;
        outb[oi]          = s01.x * inv;
        outb[HW + oi]     = s01.y * inv;
        outb[2 * HW + oi] = s2w.x * inv;
    }
}

extern "C" void kernel_launch(void* const* d_in, const int* in_sizes, int n_in,
                              void* d_out, int out_size, void* d_ws, size_t ws_size,
                              hipStream_t stream) {
    const float* image = (const float*)d_in[0];
    const float* psf   = (const float*)d_in[1];
    float* out = (float*)d_out;

    dim3 block(64, 4, 1);                  // 4 independent waves, zero barriers
    dim3 grid(NG, HH / 4, 4);              // 10 x 128 x 4 = 5120 blocks
    gauss_psf_kernel<<<grid, block, 0, stream>>>(image, psf, out);
}

// Round 7
// 81.624 us; speedup vs baseline: 1.1553x; 1.0209x over previous
//
#include <hip/hip_runtime.h>

#define HH 512
#define WW 512
#define HW (HH * WW)
#define RR 5
#define KS 11
#define EPS_F 1e-5f
#define NLOG2E 1.44269504088896340736f
#define OPW 54                // outputs per wave in x (64 lanes - 10 halo)
#define NG 10                 // column groups: 9*54 + overlap group at 458
#define RPW 2                 // output rows per wave
#define NR (KS + RPW - 1)     // 12 input rows per wave

typedef float f2 __attribute__((ext_vector_type(2)));
__device__ __forceinline__ f2 fma2(f2 a, f2 b, f2 c) { return __builtin_elementwise_fma(a, b, c); }

// R16 = R15 (zero-barrier, best 83.3) + 2 output rows per wave.
// Model update: dur_us ~= ~70us fixed harness overhead (256MiB re-poison fill
// ~44us @ 75-81% HBM + dozens of tiny reset memsets) + ~13us kernel. Evidence:
// all structural overhauls (barrier-free, VMEM, VALU-35%, staging) move dur
// by <=2us, while occupancy damage moves +10-12 => kernel is already small;
// only its per-output redundancy is left.
// This kernel shares the 12-row input pipeline (load + exp2/rcp + power
// chain) between 2 output rows: loads/output 44->24, exp2+powers/output
// 11->6; accumulation (u-select per output) unchanged. Pass H runs twice
// through the same per-wave private scratch — same-wave DS ops are in-order,
// still ZERO __syncthreads.
// VGPR: 24 f2 acc + temps ~110 < 128 cap (launch_bounds 256,4); LDS 24KB ->
// 4 blocks/CU; 2560 blocks x 4 waves = 10 waves/SIMD.
// Stop-rule: if flat (+-1us), kernel <= ~8us and dur is pinned by harness
// fills at their HBM roofline -> declare ROOFLINE.
__global__ __launch_bounds__(256, 4) void gauss_psf_kernel(const float* __restrict__ image,
                                                           const float* __restrict__ psf,
                                                           float* __restrict__ out) {
    __shared__ float4 smH[4][6][64];    // per-wave private class planes, 24 KB

    const int lane = threadIdx.x;            // 0..63
    const int ty   = threadIdx.y;            // 0..3 (wave id in block)
    const int g    = blockIdx.x;             // 0..9 column group
    const int by   = blockIdx.y;             // 0..63 (8 rows per block)
    const int yA   = by * (4 * RPW) + ty * RPW;  // wave's first output row
    const int b    = blockIdx.z;

    const int c0   = (g == NG - 1) ? (WW - OPW) : g * OPW;
    const int col  = c0 - RR + lane;         // this lane's column
    const int colc = col < 0 ? 0 : (col > WW - 1 ? WW - 1 : col);
    const float xm = ((unsigned)col < (unsigned)WW) ? 1.0f : 0.0f;

    const float* pw   = psf + (size_t)b * HW;
    const float* img0 = image + (size_t)b * 3 * HW;

    // ---- accumulators: rows A and B, 6 class pairs x (ch0,ch1,ch2,w) ----
    f2 A0[3], A1[3], A2[3], Aw[3], B0[3], B1[3], B2[3], Bw[3];
#pragma unroll
    for (int p = 0; p < 3; ++p) {
        A0[p] = (f2)0.0f; A1[p] = (f2)0.0f; A2[p] = (f2)0.0f; Aw[p] = (f2)0.0f;
        B0[p] = (f2)0.0f; B1[p] = (f2)0.0f; B2[p] = (f2)0.0f; Bw[p] = (f2)0.0f;
    }

    auto accum = [&](f2 (&a0)[3], f2 (&a1)[3], f2 (&a2)[3], f2 (&aw)[3],
                     float u, float t, float t4, float t9, float t16, float t25,
                     float i0, float i1, float i2) {
        const f2 u2  = {u, u};
        const f2 f01 = u2 * (f2){1.0f, t};                 // t^(i^2+{0,1})
        const f2 f23 = u2 * (f2){t4, t9};                  // t^(i^2+{4,9})
        const f2 f45 = u2 * (f2){t16, t25};                // t^(i^2+{16,25})
        const f2 i0v = {i0, i0}, i1v = {i1, i1}, i2v = {i2, i2};
        a0[0] = fma2(i0v, f01, a0[0]);
        a0[1] = fma2(i0v, f23, a0[1]);
        a0[2] = fma2(i0v, f45, a0[2]);
        a1[0] = fma2(i1v, f01, a1[0]);
        a1[1] = fma2(i1v, f23, a1[1]);
        a1[2] = fma2(i1v, f45, a1[2]);
        a2[0] = fma2(i2v, f01, a2[0]);
        a2[1] = fma2(i2v, f23, a2[1]);
        a2[2] = fma2(i2v, f45, a2[2]);
        aw[0] += f01;
        aw[1] += f23;
        aw[2] += f45;
    };

    // shared row pipeline: powers computed once, consumed by A (r<=10) and B (r>=1)
    auto row = [&](int r, float t, float i0, float i1, float i2) {
        const float t2 = t * t, t4 = t2 * t2, t8 = t4 * t4;
        const float t9 = t8 * t, t16 = t8 * t8, t25 = t16 * t9;
        if (r <= KS - 1) {
            const int ii = (r - RR) * (r - RR);            // constexpr after unroll
            const float u = ii == 0 ? 1.0f : ii == 1 ? t : ii == 4 ? t4
                          : ii == 9 ? t9 : ii == 16 ? t16 : t25;
            accum(A0, A1, A2, Aw, u, t, t4, t9, t16, t25, i0, i1, i2);
        }
        if (r >= 1) {
            const int ii = (r - 1 - RR) * (r - 1 - RR);    // constexpr after unroll
            const float u = ii == 0 ? 1.0f : ii == 1 ? t : ii == 4 ? t4
                          : ii == 9 ? t9 : ii == 16 ? t16 : t25;
            accum(B0, B1, B2, Bw, u, t, t4, t9, t16, t25, i0, i1, i2);
        }
    };

    if (g >= 1 && g <= 8 && by >= 1 && by <= 62) {
        // fully interior (x and y): no clamps, no masks; imm-offset row walk
        const float* pb = img0 + (size_t)(yA - RR) * WW + col;
        const float* wb = pw + (size_t)(yA - RR) * WW + col;
#pragma unroll
        for (int r = 0; r < NR; ++r) {
            const float w  = wb[r * WW];
            const float i0 = pb[r * WW];
            const float i1 = pb[r * WW + HW];
            const float i2 = pb[r * WW + 2 * HW];
            const float a = -NLOG2E * __builtin_amdgcn_rcpf(fmaf(2.0f * w, w, EPS_F));
            const float t = __builtin_amdgcn_exp2f(a);
            row(r, t, i0, i1, i2);
        }
    } else {
        // boundary blocks: per-row clamp + mask, per-lane x mask
#pragma unroll
        for (int r = 0; r < NR; ++r) {
            const int gy = yA - RR + r;
            const int ry = gy < 0 ? 0 : (gy > HH - 1 ? HH - 1 : gy);
            const float ym = ((unsigned)gy < (unsigned)HH) ? 1.0f : 0.0f;
            const int ni = ry * WW + colc;
            const float w  = pw[ni];
            const float i0 = img0[ni];
            const float i1 = img0[ni + HW];
            const float i2 = img0[ni + 2 * HW];
            const float a = -NLOG2E * __builtin_amdgcn_rcpf(fmaf(2.0f * w, w, EPS_F));
            const float t = xm * ym * __builtin_amdgcn_exp2f(a);
            row(r, t, i0, i1, i2);
        }
    }

    // ---- Pass H (twice, same per-wave scratch; same-wave DS ops are in-order,
    //      compiler lgkmcnt handles RAW — no barrier anywhere) ----
    const int lm = lane - RR;
    const int lb = lm < 0 ? 0 : (lm > OPW - 1 ? OPW - 1 : lm);
    float* outb = out + (size_t)b * 3 * HW;

    auto passH = [&](f2 (&a0)[3], f2 (&a1)[3], f2 (&a2)[3], f2 (&aw)[3], int y) {
#pragma unroll
        for (int p = 0; p < 3; ++p) {                      // 6 ds_write_b128
            smH[ty][2 * p][lane]     = make_float4(a0[p].x, a1[p].x, a2[p].x, aw[p].x);
            smH[ty][2 * p + 1][lane] = make_float4(a0[p].y, a1[p].y, a2[p].y, aw[p].y);
        }
        f2 s01 = (f2)0.0f, s2w = (f2)0.0f;
#pragma unroll
        for (int j = 0; j < KS; ++j) {
            const int jj = (j - RR) * (j - RR);            // constexpr
            const int ai = jj == 0 ? 0 : jj == 1 ? 1 : jj == 4 ? 2
                         : jj == 9 ? 3 : jj == 16 ? 4 : 5;
            const float4 v = smH[ty][ai][lb + j];          // ds_read_b128, imm off
            s01 += (f2){v.x, v.y};                         // pk_add
            s2w += (f2){v.z, v.w};
        }
        if ((unsigned)lm < OPW) {                          // lanes 5..58 store
            const float swv = s2w.y;                       // >= 1 (center tap)
            float inv = __builtin_amdgcn_rcpf(swv);
            inv = inv * (2.0f - swv * inv);                // Newton: ~1e-7 rel
            const int oi = y * WW + col;                   // col in [0,511] here
            outb[oi]          = s01.x * inv;
            outb[HW + oi]     = s01.y * inv;
            outb[2 * HW + oi] = s2w.x * inv;
        }
    };

    passH(A0, A1, A2, Aw, yA);
    passH(B0, B1, B2, Bw, yA + 1);
}

extern "C" void kernel_launch(void* const* d_in, const int* in_sizes, int n_in,
                              void* d_out, int out_size, void* d_ws, size_t ws_size,
                              hipStream_t stream) {
    const float* image = (const float*)d_in[0];
    const float* psf   = (const float*)d_in[1];
    float* out = (float*)d_out;

    dim3 block(64, 4, 1);                  // 4 independent waves, zero barriers
    dim3 grid(NG, HH / (4 * RPW), 4);      // 10 x 64 x 4 = 2560 blocks
    gauss_psf_kernel<<<grid, block, 0, stream>>>(image, psf, out);
}